// Round 8
// baseline (180.395 us; speedup 1.0000x reference)
//
#include <hip/hip_runtime.h>
#include <stdint.h>

typedef unsigned short u16;
typedef __bf16 bf16x8 __attribute__((ext_vector_type(8)));
typedef unsigned short u16x8 __attribute__((ext_vector_type(8)));
typedef float f32x4 __attribute__((ext_vector_type(4)));
typedef uint32_t u32v4 __attribute__((ext_vector_type(4)));

#define LOG2E 1.4426950408889634f

typedef const __attribute__((address_space(1))) uint32_t as1_u32;
typedef __attribute__((address_space(3))) uint32_t as3_u32;

// float -> bf16 round-to-nearest-even
__device__ __forceinline__ u16 f2bf(float f) {
  union { float f; uint32_t i; } v; v.f = f;
  uint32_t r = (v.i + 0x7fffu + ((v.i >> 16) & 1u)) >> 16;
  return (u16)r;
}
__device__ __forceinline__ float bf2f(u16 u) {
  union { uint32_t i; float f; } v; v.i = ((uint32_t)u) << 16; return v.f;
}

// async global->LDS, 16B/lane. LDS dest = wave-uniform base; HW scatters
// lane i to base + i*16B.
__device__ __forceinline__ void gld_lds16(const void* g, void* l) {
  as1_u32* gp = (as1_u32*)((uintptr_t)g);
  as3_u32* lp = (as3_u32*)(uint32_t)(uintptr_t)(l);
  __builtin_amdgcn_global_load_lds(gp, lp, 16, 0, 0);
}

// raw v_exp_f32 (2^x), no libm clamp path — inputs bounded here
__device__ __forceinline__ float fast_exp2(float x) {
  float r;
  asm("v_exp_f32 %0, %1" : "=v"(r) : "v"(x));
  return r;
}

// ---------------------------------------------------------------------------
// Kernel 0: f32 -> bf16 convert (z=0..3) + zero d_out (z=4) + zero lacc (z=5).
// Zeroing is required because flash_attn split-K accumulates into out/lacc
// with f32 atomicAdd.
// ---------------------------------------------------------------------------
__global__ __launch_bounds__(256) void f32_to_bf16(
    const float* __restrict__ x, const float* __restrict__ wq,
    const float* __restrict__ wk, const float* __restrict__ wv,
    u16* __restrict__ xc, u16* __restrict__ wqc,
    u16* __restrict__ wkc, u16* __restrict__ wvc,
    float* __restrict__ oz, float* __restrict__ lz) {
  const int z = blockIdx.y;
  const int idx = (blockIdx.x * 256 + (int)threadIdx.x) * 8;
  if (z >= 4) {
    const f32x4 zz = {0.f, 0.f, 0.f, 0.f};
    if (z == 4) {                       // out: 4096*1024 f32
      *(f32x4*)&oz[idx] = zz; *(f32x4*)&oz[idx + 4] = zz;
    } else if (idx < 65536) {           // lacc: [b][t][h] f32
      *(f32x4*)&lz[idx] = zz; *(f32x4*)&lz[idx + 4] = zz;
    }
    return;
  }
  const float* src = z == 0 ? x : (z == 1 ? wq : (z == 2 ? wk : wv));
  u16* dst = z == 0 ? xc : (z == 1 ? wqc : (z == 2 ? wkc : wvc));
  const int n = z == 0 ? (1 << 22) : (1 << 20);
  if (idx >= n) return;
  const f32x4 a = *(const f32x4*)&src[idx];
  const f32x4 b = *(const f32x4*)&src[idx + 4];
  u16x8 o;
#pragma unroll
  for (int j = 0; j < 4; j++) { o[j] = f2bf(a[j]); o[j + 4] = f2bf(b[j]); }
  *(u16x8*)&dst[idx] = o;
}

// ---------------------------------------------------------------------------
// Kernel 1: QKV GEMM, 128x128 tile, BK=64, XOR-swizzled LDS, plain epilogue.
// Flat grid 768, XCD-aware decode (R7, passing).
// ---------------------------------------------------------------------------
__global__ __launch_bounds__(256) void qkv_gemm(
    const u16* __restrict__ xc, const u16* __restrict__ wqc,
    const u16* __restrict__ wkc, const u16* __restrict__ wvc,
    u16* __restrict__ qo, u16* __restrict__ ko, u16* __restrict__ vt) {
  __shared__ __align__(16) u16 As[128 * 64];
  __shared__ __align__(16) u16 Bs[128 * 64];

  const int tid = threadIdx.x;
  const int lane = tid & 63;
  const int w = tid >> 6;
  const int wm = w >> 1, wn = w & 1;
  const int quad = lane >> 4, m16 = lane & 15;

  const int id    = (int)blockIdx.x;      // 0..767
  const int xcd   = id & 7;
  const int local = id >> 3;              // 0..95
  const int by    = xcd * 4 + (local & 3);
  const int rest  = local >> 2;           // 0..23
  const int which = rest % 3;
  const int bx    = rest / 3;             // 0..7

  const u16* __restrict__ Ap;
  const u16* __restrict__ Bp;
  int m0, n0;
  if (which == 2) {
    Ap = wvc; Bp = xc;
    m0 = bx * 128;   // Wv rows (1024)
    n0 = by * 128;   // x rows (4096)
  } else {
    Ap = xc; Bp = which == 0 ? wqc : wkc;
    m0 = by * 128;   // x rows
    n0 = bx * 128;   // W rows
  }

  const f32x4 z4 = {0.f, 0.f, 0.f, 0.f};
  f32x4 acc[4][4];
#pragma unroll
  for (int i = 0; i < 4; i++)
#pragma unroll
    for (int j = 0; j < 4; j++) acc[i][j] = z4;

  const int lrow = lane >> 3;                       // 0..7
  const int scol = ((lane & 7) ^ (lrow & 7)) * 8;   // pre-swizzled src chunk
  const int srowA = m0 + w * 32 + lrow;
  const int srowB = n0 + w * 32 + lrow;
  const int rsw = m16 & 7;

  for (int k0 = 0; k0 < 1024; k0 += 64) {
    __syncthreads();  // prior MFMA reads of As/Bs complete
#pragma unroll
    for (int j = 0; j < 4; j++) {
      gld_lds16(&Ap[(size_t)(srowA + j * 8) * 1024 + k0 + scol],
                &As[(w * 32 + j * 8) * 64]);
      gld_lds16(&Bp[(size_t)(srowB + j * 8) * 1024 + k0 + scol],
                &Bs[(w * 32 + j * 8) * 64]);
    }
    __syncthreads();  // drains vmcnt -> tiles ready

#pragma unroll
    for (int kk = 0; kk < 2; kk++) {
      bf16x8 af[4], bfr[4];
#pragma unroll
      for (int t = 0; t < 4; t++) {
        af[t] = *(const bf16x8*)
            &As[(wm * 64 + t * 16 + m16) * 64 + (((kk * 4 + quad) ^ rsw) * 8)];
        bfr[t] = *(const bf16x8*)
            &Bs[(wn * 64 + t * 16 + m16) * 64 + (((kk * 4 + quad) ^ rsw) * 8)];
      }
#pragma unroll
      for (int mt = 0; mt < 4; mt++)
#pragma unroll
        for (int nt = 0; nt < 4; nt++)
          acc[mt][nt] = __builtin_amdgcn_mfma_f32_16x16x32_bf16(
              af[mt], bfr[nt], acc[mt][nt], 0, 0, 0);
    }
  }

  if (which < 2) {
    u16* __restrict__ out = which == 0 ? qo : ko;
#pragma unroll
    for (int mt = 0; mt < 4; mt++) {
      const int row = m0 + wm * 64 + mt * 16 + quad * 4;
#pragma unroll
      for (int nt = 0; nt < 4; nt++) {
        const int n = n0 + wn * 64 + nt * 16 + m16;
        f32x4 a = acc[mt][nt];
#pragma unroll
        for (int r = 0; r < 4; r++)
          out[(size_t)(row + r) * 1024 + n] = f2bf(a[r]);
      }
    }
  } else {
    const int m16p = (m16 & 3) | ((m16 & 4) << 1) | ((m16 & 8) >> 1);
#pragma unroll
    for (int mt = 0; mt < 4; mt++) {
      const int row = m0 + wm * 64 + mt * 16 + quad * 4;  // d index
#pragma unroll
      for (int nt = 0; nt < 4; nt++) {
        const int n = n0 + wn * 64 + nt * 16 + m16p;      // x row (permuted)
        f32x4 a = acc[mt][nt];
#pragma unroll
        for (int r = 0; r < 4; r++)
          vt[(size_t)(row + r) * 4096 + n] = f2bf(a[r]);
      }
    }
  }
}

// ---------------------------------------------------------------------------
// Kernel 2: RoPE in-place, standalone (R5 proven): u16x8 + HW trig.
// ---------------------------------------------------------------------------
__global__ __launch_bounds__(256) void rope_inplace(u16* __restrict__ qb,
                                                    u16* __restrict__ kb) {
  u16* buf = blockIdx.y == 0 ? qb : kb;
  const int p = blockIdx.x * 256 + (int)threadIdx.x;
  const int e0 = p * 8;
  const int row = e0 >> 10;
  const int col0 = e0 & 1023;
  const int t = row & 2047;
  const float tf = (float)t;

  u16x8 d = *(const u16x8*)&buf[(size_t)row * 1024 + col0];
  u16x8 o;
#pragma unroll
  for (int j = 0; j < 4; j++) {
    const int i = ((col0 & 63) >> 1) + j;
    const float th = fast_exp2(-(float)i * 0.02595256324130752f);
    const float rev = tf * th * 0.15915494309189535f;
    float fr, s, c;
    asm("v_fract_f32 %0, %1" : "=v"(fr) : "v"(rev));
    asm("v_sin_f32 %0, %1" : "=v"(s) : "v"(fr));
    asm("v_cos_f32 %0, %1" : "=v"(c) : "v"(fr));
    const float a0 = bf2f(d[2 * j]), a1 = bf2f(d[2 * j + 1]);
    o[2 * j]     = f2bf(a0 * c - a1 * s);
    o[2 * j + 1] = f2bf(a1 * c + a0 * s);
  }
  *(u16x8*)&buf[(size_t)row * 1024 + col0] = o;
}

// ---------------------------------------------------------------------------
// Kernel 3: causal flash attention — SPLIT-K over key chunks (R7 lesson:
// occupancy 11% = long blocks run ALONE at the tail; critical path = 16
// serial rounds of the Q=15 block). Block (Q,c) does rounds [4c, min(4c+4,
// Q+1)) — 40 items x 32 (b,h) = 1280 blocks, every block <= 4 serial rounds;
// scheduler backfills so CUs keep 2 active blocks throughout. NO-RESCALE
// softmax makes partials combinable by PLAIN SUM: O/l atomicAdd'd (f32) into
// the zeroed out/lacc; attn_norm divides afterwards. Numerics = R7 modulo
// f32 add order. Inner round body: R7 double-buffer, 1 barrier, in-reg P,
// l via ones-MFMA, fast exp2. XCD locality: id&7 = XCD sees 4 heads.
// ---------------------------------------------------------------------------
__global__ __launch_bounds__(256, 2) void flash_attn(
    const u16* __restrict__ qg, const u16* __restrict__ kg,
    const u16* __restrict__ vt, float* __restrict__ out,
    float* __restrict__ lacc) {
  __shared__ __align__(16) u16 Ks[2][128 * 72];   // [key][d]
  __shared__ __align__(16) u16 Vs[2][64 * 136];   // [d][kperm] (vt pre-swz)

  const int tid = threadIdx.x, lane = tid & 63, w = tid >> 6;
  const int quad = lane >> 4, m16 = lane & 15;

  const int id   = (int)blockIdx.x;  // 0..1279
  const int X    = id & 7;           // XCD
  const int rem  = id >> 3;          // 0..159
  const int vloc = rem & 3;
  const int item = 39 - (rem >> 2);  // 0..39, LPT-ish (big Q first)
  int Q, cc;
  if (item < 4)        { Q = item;                 cc = 0; }
  else if (item < 12)  { const int t = item - 4;  Q = 4 + (t >> 1); cc = t & 1; }
  else if (item < 24)  { const int t = item - 12; Q = 8 + t / 3;    cc = t % 3; }
  else                 { const int t = item - 24; Q = 12 + (t >> 2); cc = t & 3; }
  const int v    = X * 4 + vloc;     // (b,h) combo
  const int h    = v & 15;
  const int b    = v >> 4;

  const size_t base  = (size_t)b * 2048 * 1024 + (size_t)h * 64;
  const size_t vbase = (size_t)(h * 64) * 4096 + (size_t)b * 2048;
  const float SC = 0.03125f * LOG2E;
  const f32x4 z4 = {0.f, 0.f, 0.f, 0.f};
  const int srow = tid >> 2, sc = (tid & 3) * 16;

  union { u16x8 u; bf16x8 f; } ones;
#pragma unroll
  for (int k = 0; k < 8; k++) ones.u[k] = 0x3F80;  // bf16 1.0

  const int q0 = Q * 128;
  const int r0 = cc * 4;
  const int r1 = min(r0 + 4, Q + 1);   // chunk-local end (rounds of 128 keys)

  // Q fragments for both subtiles, straight from global (L2-hit).
  const u16* qsA = &qg[base + (size_t)(q0 + w * 32 + m16) * 1024 + quad * 8];
  const bf16x8 qfA0 = *(const bf16x8*)qsA;
  const bf16x8 qfA1 = *(const bf16x8*)(qsA + 32);
  const u16* qsB = qsA + (size_t)16 * 1024;
  const bf16x8 qfB0 = *(const bf16x8*)qsB;
  const bf16x8 qfB1 = *(const bf16x8*)(qsB + 32);

  // Prefetch first chunk round into regs.
  u16x8 kr0, kr1, kr2, kr3, vr0, vr1, vr2, vr3;
  {
    const int kb0 = r0 * 128;
    const u16* ks = &kg[base + (size_t)(kb0 + srow) * 1024 + sc];
    kr0 = *(const u16x8*)ks; kr1 = *(const u16x8*)(ks + 8);
    const u16* ks2 = ks + (size_t)64 * 1024;
    kr2 = *(const u16x8*)ks2; kr3 = *(const u16x8*)(ks2 + 8);
    const u16* vs = &vt[vbase + (size_t)srow * 4096 + kb0 + sc];
    vr0 = *(const u16x8*)vs; vr1 = *(const u16x8*)(vs + 8);
    vr2 = *(const u16x8*)(vs + 64); vr3 = *(const u16x8*)(vs + 72);
  }

  f32x4 lA = z4, lB = z4;
  f32x4 OA[4], OB[4];
#pragma unroll
  for (int d = 0; d < 4; d++) { OA[d] = z4; OB[d] = z4; }

  const int qrowA = q0 + w * 32 + quad * 4;  // O rows (subtile A)
  const int qcolA = q0 + w * 32 + m16;       // softmax q (subtile A)

  int p = 0;
  for (int rr = r0; rr < r1; ++rr) {
    const int k0 = rr * 128;
    // stage round rr into buf p (overlaps other waves' prior-round compute)
    u16* ksp = &Ks[p][0];
    u16* vsp = &Vs[p][0];
    *(u16x8*)&ksp[srow * 72 + sc] = kr0;
    *(u16x8*)&ksp[srow * 72 + sc + 8] = kr1;
    *(u16x8*)&ksp[(64 + srow) * 72 + sc] = kr2;
    *(u16x8*)&ksp[(64 + srow) * 72 + sc + 8] = kr3;
    *(u16x8*)&vsp[srow * 136 + sc] = vr0;
    *(u16x8*)&vsp[srow * 136 + sc + 8] = vr1;
    *(u16x8*)&vsp[srow * 136 + 64 + sc] = vr2;
    *(u16x8*)&vsp[srow * 136 + 64 + sc + 8] = vr3;
    if (rr + 1 < r1) {  // prefetch next round
      const u16* ks = &kg[base + (size_t)(k0 + 128 + srow) * 1024 + sc];
      kr0 = *(const u16x8*)ks; kr1 = *(const u16x8*)(ks + 8);
      const u16* ks2 = ks + (size_t)64 * 1024;
      kr2 = *(const u16x8*)ks2; kr3 = *(const u16x8*)(ks2 + 8);
      const u16* vs = &vt[vbase + (size_t)srow * 4096 + k0 + 128 + sc];
      vr0 = *(const u16x8*)vs; vr1 = *(const u16x8*)(vs + 8);
      vr2 = *(const u16x8*)(vs + 64); vr3 = *(const u16x8*)(vs + 72);
    }
    __syncthreads();  // single barrier: buf p staged; prior buf reads done

    // S^T = K Q^T over 128 keys for BOTH subtiles; K frags read ONCE.
    f32x4 SA[8], SB[8];
#pragma unroll
    for (int nt = 0; nt < 8; nt++) {
      const bf16x8 kf0 = *(const bf16x8*)&ksp[(nt * 16 + m16) * 72 + quad * 8];
      const bf16x8 kf1 =
          *(const bf16x8*)&ksp[(nt * 16 + m16) * 72 + 32 + quad * 8];
      SA[nt] = __builtin_amdgcn_mfma_f32_16x16x32_bf16(kf0, qfA0, z4, 0, 0, 0);
      SA[nt] = __builtin_amdgcn_mfma_f32_16x16x32_bf16(kf1, qfA1, SA[nt], 0, 0, 0);
      SB[nt] = __builtin_amdgcn_mfma_f32_16x16x32_bf16(kf0, qfB0, z4, 0, 0, 0);
      SB[nt] = __builtin_amdgcn_mfma_f32_16x16x32_bf16(kf1, qfB1, SB[nt], 0, 0, 0);
    }

    const bool lastr = (rr == Q);  // diagonal round (global, not chunk-local)

    union { u32v4 u; bf16x8 f; } PA[4], PB[4];
    {  // subtile A
      uint32_t W[16];
#pragma unroll
      for (int nt = 0; nt < 8; nt++) {
        float pe[4];
#pragma unroll
        for (int r = 0; r < 4; r++) {
          float e = fast_exp2(SA[nt][r] * SC);
          const int key = k0 + nt * 16 + quad * 4 + r;
          if (lastr && key > qcolA) e = 0.f;
          pe[r] = e;
        }
        uint32_t w0, w1;
        asm("v_cvt_pk_bf16_f32 %0, %1, %2" : "=v"(w0) : "v"(pe[0]), "v"(pe[1]));
        asm("v_cvt_pk_bf16_f32 %0, %1, %2" : "=v"(w1) : "v"(pe[2]), "v"(pe[3]));
        W[2 * nt] = w0; W[2 * nt + 1] = w1;
      }
#pragma unroll
      for (int ks = 0; ks < 4; ks++) {
        uint32_t a0 = W[4 * ks], b0 = W[4 * ks + 2];
        uint32_t a1 = W[4 * ks + 1], b1 = W[4 * ks + 3];
        asm("v_permlane32_swap_b32 %0, %1" : "+v"(a0), "+v"(b0));
        asm("v_permlane32_swap_b32 %0, %1" : "+v"(a1), "+v"(b1));
        PA[ks].u = (u32v4){a0, a1, b0, b1};
      }
    }
    {  // subtile B
      const int qcolB = qcolA + 16;
      uint32_t W[16];
#pragma unroll
      for (int nt = 0; nt < 8; nt++) {
        float pe[4];
#pragma unroll
        for (int r = 0; r < 4; r++) {
          float e = fast_exp2(SB[nt][r] * SC);
          const int key = k0 + nt * 16 + quad * 4 + r;
          if (lastr && key > qcolB) e = 0.f;
          pe[r] = e;
        }
        uint32_t w0, w1;
        asm("v_cvt_pk_bf16_f32 %0, %1, %2" : "=v"(w0) : "v"(pe[0]), "v"(pe[1]));
        asm("v_cvt_pk_bf16_f32 %0, %1, %2" : "=v"(w1) : "v"(pe[2]), "v"(pe[3]));
        W[2 * nt] = w0; W[2 * nt + 1] = w1;
      }
#pragma unroll
      for (int ks = 0; ks < 4; ks++) {
        uint32_t a0 = W[4 * ks], b0 = W[4 * ks + 2];
        uint32_t a1 = W[4 * ks + 1], b1 = W[4 * ks + 3];
        asm("v_permlane32_swap_b32 %0, %1" : "+v"(a0), "+v"(b0));
        asm("v_permlane32_swap_b32 %0, %1" : "+v"(a1), "+v"(b1));
        PB[ks].u = (u32v4){a0, a1, b0, b1};
      }
    }

    // l += P * ones (partial row sums of rounded P)
#pragma unroll
    for (int ks = 0; ks < 4; ks++) {
      lA = __builtin_amdgcn_mfma_f32_16x16x32_bf16(PA[ks].f, ones.f, lA, 0, 0, 0);
      lB = __builtin_amdgcn_mfma_f32_16x16x32_bf16(PB[ks].f, ones.f, lB, 0, 0, 0);
    }

    // O += P V; V frags read ONCE, feed both subtiles.
#pragma unroll
    for (int dt = 0; dt < 4; dt++) {
#pragma unroll
      for (int ks = 0; ks < 4; ks++) {
        const bf16x8 vf =
            *(const bf16x8*)&vsp[(dt * 16 + m16) * 136 + ks * 32 + quad * 8];
        OA[dt] = __builtin_amdgcn_mfma_f32_16x16x32_bf16(PA[ks].f, vf, OA[dt],
                                                         0, 0, 0);
        OB[dt] = __builtin_amdgcn_mfma_f32_16x16x32_bf16(PB[ks].f, vf, OB[dt],
                                                         0, 0, 0);
      }
    }
    p ^= 1;
  }

  // Combine: plain-sum partials (no-rescale softmax => no max merge needed).
#pragma unroll
  for (int dt = 0; dt < 4; dt++)
#pragma unroll
    for (int r = 0; r < 4; r++) {
      atomicAdd(&out[base + (size_t)(qrowA + r) * 1024 + dt * 16 + m16],
                OA[dt][r]);
      atomicAdd(&out[base + (size_t)(qrowA + 16 + r) * 1024 + dt * 16 + m16],
                OB[dt][r]);
    }
  if (m16 == 0) {
#pragma unroll
    for (int r = 0; r < 4; r++) {
      atomicAdd(&lacc[((size_t)b * 2048 + qrowA + r) * 16 + h], lA[r]);
      atomicAdd(&lacc[((size_t)b * 2048 + qrowA + 16 + r) * 16 + h], lB[r]);
    }
  }
}

// ---------------------------------------------------------------------------
// Kernel 4: normalize out in place: out[(b,t,h,d)] /= lacc[(b,t,h)].
// ---------------------------------------------------------------------------
__global__ __launch_bounds__(256) void attn_norm(float* __restrict__ out,
                                                 const float* __restrict__ lacc) {
  const int e0 = (blockIdx.x * 256 + (int)threadIdx.x) * 8;
  const float inv = 1.0f / lacc[e0 >> 6];
  f32x4 a = *(const f32x4*)&out[e0];
  f32x4 b = *(const f32x4*)&out[e0 + 4];
#pragma unroll
  for (int j = 0; j < 4; j++) { a[j] *= inv; b[j] *= inv; }
  *(f32x4*)&out[e0] = a;
  *(f32x4*)&out[e0 + 4] = b;
}

extern "C" void kernel_launch(void* const* d_in, const int* in_sizes, int n_in,
                              void* d_out, int out_size, void* d_ws, size_t ws_size,
                              hipStream_t stream) {
  const float* x  = (const float*)d_in[0];
  const float* Wq = (const float*)d_in[1];
  const float* Wk = (const float*)d_in[2];
  const float* Wv = (const float*)d_in[3];
  u16* qb  = (u16*)d_ws;                    // [4096][1024] bf16
  u16* kb  = qb  + (size_t)4096 * 1024;     // [4096][1024] bf16
  u16* vtw = kb  + (size_t)4096 * 1024;     // [1024][4096] bf16 (V^T, swap23)
  u16* xc  = vtw + (size_t)4096 * 1024;     // bf16 inputs
  u16* wqc = xc  + (size_t)4096 * 1024;
  u16* wkc = wqc + (size_t)1024 * 1024;
  u16* wvc = wkc + (size_t)1024 * 1024;
  float* lacc = (float*)(wvc + (size_t)1024 * 1024);  // [2][2048][16] f32
  float* outf = (float*)d_out;

  f32_to_bf16<<<dim3(2048, 6), 256, 0, stream>>>(x, Wq, Wk, Wv,
                                                 xc, wqc, wkc, wvc,
                                                 outf, lacc);
  qkv_gemm<<<dim3(768, 1, 1), 256, 0, stream>>>(xc, wqc, wkc, wvc,
                                                qb, kb, vtw);
  rope_inplace<<<dim3(2048, 2), 256, 0, stream>>>(qb, kb);
  flash_attn<<<dim3(1280, 1, 1), 256, 0, stream>>>(qb, kb, vtw, outf, lacc);
  attn_norm<<<dim3(2048, 1, 1), 256, 0, stream>>>(outf, lacc);
}

// Round 9
// 152.663 us; speedup vs baseline: 1.1817x; 1.1817x over previous
//
#include <hip/hip_runtime.h>
#include <stdint.h>

typedef unsigned short u16;
typedef __bf16 bf16x8 __attribute__((ext_vector_type(8)));
typedef unsigned short u16x8 __attribute__((ext_vector_type(8)));
typedef float f32x4 __attribute__((ext_vector_type(4)));
typedef uint32_t u32v4 __attribute__((ext_vector_type(4)));

#define LOG2E 1.4426950408889634f

typedef const __attribute__((address_space(1))) uint32_t as1_u32;
typedef __attribute__((address_space(3))) uint32_t as3_u32;

// float -> bf16 round-to-nearest-even
__device__ __forceinline__ u16 f2bf(float f) {
  union { float f; uint32_t i; } v; v.f = f;
  uint32_t r = (v.i + 0x7fffu + ((v.i >> 16) & 1u)) >> 16;
  return (u16)r;
}
__device__ __forceinline__ float bf2f(u16 u) {
  union { uint32_t i; float f; } v; v.i = ((uint32_t)u) << 16; return v.f;
}

// async global->LDS, 16B/lane. LDS dest = wave-uniform base; HW scatters
// lane i to base + i*16B.
__device__ __forceinline__ void gld_lds16(const void* g, void* l) {
  as1_u32* gp = (as1_u32*)((uintptr_t)g);
  as3_u32* lp = (as3_u32*)(uint32_t)(uintptr_t)(l);
  __builtin_amdgcn_global_load_lds(gp, lp, 16, 0, 0);
}

// raw v_exp_f32 (2^x), no libm clamp path — inputs bounded here
__device__ __forceinline__ float fast_exp2(float x) {
  float r;
  asm("v_exp_f32 %0, %1" : "=v"(r) : "v"(x));
  return r;
}

// ---------------------------------------------------------------------------
// Kernel 0: f32 -> bf16 convert.
// ---------------------------------------------------------------------------
__global__ __launch_bounds__(256) void f32_to_bf16(
    const float* __restrict__ x, const float* __restrict__ wq,
    const float* __restrict__ wk, const float* __restrict__ wv,
    u16* __restrict__ xc, u16* __restrict__ wqc,
    u16* __restrict__ wkc, u16* __restrict__ wvc) {
  const int z = blockIdx.y;
  const float* src = z == 0 ? x : (z == 1 ? wq : (z == 2 ? wk : wv));
  u16* dst = z == 0 ? xc : (z == 1 ? wqc : (z == 2 ? wkc : wvc));
  const int n = z == 0 ? (1 << 22) : (1 << 20);

  const int idx = (blockIdx.x * 256 + (int)threadIdx.x) * 8;
  if (idx >= n) return;
  const f32x4 a = *(const f32x4*)&src[idx];
  const f32x4 b = *(const f32x4*)&src[idx + 4];
  u16x8 o;
#pragma unroll
  for (int j = 0; j < 4; j++) { o[j] = f2bf(a[j]); o[j + 4] = f2bf(b[j]); }
  *(u16x8*)&dst[idx] = o;
}

// ---------------------------------------------------------------------------
// Kernel 1: QKV GEMM, 128x128 tile, BK=64, XOR-swizzled LDS, plain epilogue.
// Flat grid 768, XCD-aware decode (R7, passing).
// ---------------------------------------------------------------------------
__global__ __launch_bounds__(256) void qkv_gemm(
    const u16* __restrict__ xc, const u16* __restrict__ wqc,
    const u16* __restrict__ wkc, const u16* __restrict__ wvc,
    u16* __restrict__ qo, u16* __restrict__ ko, u16* __restrict__ vt) {
  __shared__ __align__(16) u16 As[128 * 64];
  __shared__ __align__(16) u16 Bs[128 * 64];

  const int tid = threadIdx.x;
  const int lane = tid & 63;
  const int w = tid >> 6;
  const int wm = w >> 1, wn = w & 1;
  const int quad = lane >> 4, m16 = lane & 15;

  const int id    = (int)blockIdx.x;      // 0..767
  const int xcd   = id & 7;
  const int local = id >> 3;              // 0..95
  const int by    = xcd * 4 + (local & 3);
  const int rest  = local >> 2;           // 0..23
  const int which = rest % 3;
  const int bx    = rest / 3;             // 0..7

  const u16* __restrict__ Ap;
  const u16* __restrict__ Bp;
  int m0, n0;
  if (which == 2) {
    Ap = wvc; Bp = xc;
    m0 = bx * 128;   // Wv rows (1024)
    n0 = by * 128;   // x rows (4096)
  } else {
    Ap = xc; Bp = which == 0 ? wqc : wkc;
    m0 = by * 128;   // x rows
    n0 = bx * 128;   // W rows
  }

  const f32x4 z4 = {0.f, 0.f, 0.f, 0.f};
  f32x4 acc[4][4];
#pragma unroll
  for (int i = 0; i < 4; i++)
#pragma unroll
    for (int j = 0; j < 4; j++) acc[i][j] = z4;

  const int lrow = lane >> 3;                       // 0..7
  const int scol = ((lane & 7) ^ (lrow & 7)) * 8;   // pre-swizzled src chunk
  const int srowA = m0 + w * 32 + lrow;
  const int srowB = n0 + w * 32 + lrow;
  const int rsw = m16 & 7;

  for (int k0 = 0; k0 < 1024; k0 += 64) {
    __syncthreads();  // prior MFMA reads of As/Bs complete
#pragma unroll
    for (int j = 0; j < 4; j++) {
      gld_lds16(&Ap[(size_t)(srowA + j * 8) * 1024 + k0 + scol],
                &As[(w * 32 + j * 8) * 64]);
      gld_lds16(&Bp[(size_t)(srowB + j * 8) * 1024 + k0 + scol],
                &Bs[(w * 32 + j * 8) * 64]);
    }
    __syncthreads();  // drains vmcnt -> tiles ready

#pragma unroll
    for (int kk = 0; kk < 2; kk++) {
      bf16x8 af[4], bfr[4];
#pragma unroll
      for (int t = 0; t < 4; t++) {
        af[t] = *(const bf16x8*)
            &As[(wm * 64 + t * 16 + m16) * 64 + (((kk * 4 + quad) ^ rsw) * 8)];
        bfr[t] = *(const bf16x8*)
            &Bs[(wn * 64 + t * 16 + m16) * 64 + (((kk * 4 + quad) ^ rsw) * 8)];
      }
#pragma unroll
      for (int mt = 0; mt < 4; mt++)
#pragma unroll
        for (int nt = 0; nt < 4; nt++)
          acc[mt][nt] = __builtin_amdgcn_mfma_f32_16x16x32_bf16(
              af[mt], bfr[nt], acc[mt][nt], 0, 0, 0);
    }
  }

  if (which < 2) {
    u16* __restrict__ out = which == 0 ? qo : ko;
#pragma unroll
    for (int mt = 0; mt < 4; mt++) {
      const int row = m0 + wm * 64 + mt * 16 + quad * 4;
#pragma unroll
      for (int nt = 0; nt < 4; nt++) {
        const int n = n0 + wn * 64 + nt * 16 + m16;
        f32x4 a = acc[mt][nt];
#pragma unroll
        for (int r = 0; r < 4; r++)
          out[(size_t)(row + r) * 1024 + n] = f2bf(a[r]);
      }
    }
  } else {
    const int m16p = (m16 & 3) | ((m16 & 4) << 1) | ((m16 & 8) >> 1);
#pragma unroll
    for (int mt = 0; mt < 4; mt++) {
      const int row = m0 + wm * 64 + mt * 16 + quad * 4;  // d index
#pragma unroll
      for (int nt = 0; nt < 4; nt++) {
        const int n = n0 + wn * 64 + nt * 16 + m16p;      // x row (permuted)
        f32x4 a = acc[mt][nt];
#pragma unroll
        for (int r = 0; r < 4; r++)
          vt[(size_t)(row + r) * 4096 + n] = f2bf(a[r]);
      }
    }
  }
}

// ---------------------------------------------------------------------------
// Kernel 2: RoPE in-place, standalone (R5 proven): u16x8 + HW trig.
// ---------------------------------------------------------------------------
__global__ __launch_bounds__(256) void rope_inplace(u16* __restrict__ qb,
                                                    u16* __restrict__ kb) {
  u16* buf = blockIdx.y == 0 ? qb : kb;
  const int p = blockIdx.x * 256 + (int)threadIdx.x;
  const int e0 = p * 8;
  const int row = e0 >> 10;
  const int col0 = e0 & 1023;
  const int t = row & 2047;
  const float tf = (float)t;

  u16x8 d = *(const u16x8*)&buf[(size_t)row * 1024 + col0];
  u16x8 o;
#pragma unroll
  for (int j = 0; j < 4; j++) {
    const int i = ((col0 & 63) >> 1) + j;
    const float th = fast_exp2(-(float)i * 0.02595256324130752f);
    const float rev = tf * th * 0.15915494309189535f;
    float fr, s, c;
    asm("v_fract_f32 %0, %1" : "=v"(fr) : "v"(rev));
    asm("v_sin_f32 %0, %1" : "=v"(s) : "v"(fr));
    asm("v_cos_f32 %0, %1" : "=v"(c) : "v"(fr));
    const float a0 = bf2f(d[2 * j]), a1 = bf2f(d[2 * j + 1]);
    o[2 * j]     = f2bf(a0 * c - a1 * s);
    o[2 * j + 1] = f2bf(a1 * c + a0 * s);
  }
  *(u16x8*)&buf[(size_t)row * 1024 + col0] = o;
}

// ---------------------------------------------------------------------------
// Kernel 3: causal flash attention — R7 structure EXACTLY (32 q-rows/wave,
// 128-row blocks, KVBLK=128, double-buffered LDS, 1 barrier/round, in-reg P,
// l via ones-MFMA, fast exp2). ONLY the index decode changes:
// R8 post-mortem found HW round-robin dispatch puts blocks id and id+256 on
// the SAME CU, and R7's decode gave that pair {Q=kk,Q=kk+4} / {15-kk,11-kk}
// — both-short or both-long (per-CU work 6..28 rounds; the 28-round CUs set
// the 45.8us wall clock; 11% occupancy = short CUs idling). New decode:
// complement bit j = id>>8, so co-resident blocks (lower,j=0)/(lower,j=1)
// have Q = kk and 15-kk, SAME (b,h), same XCD -> every CU owns exactly 17
// rounds with both blocks alive throughout. Pure remap: zero numerics
// change; mapping affects only speed, never correctness.
// ---------------------------------------------------------------------------
__global__ __launch_bounds__(256, 2) void flash_attn(
    const u16* __restrict__ qg, const u16* __restrict__ kg,
    const u16* __restrict__ vt, float* __restrict__ out) {
  __shared__ __align__(16) u16 Ks[2][128 * 72];   // [key][d]
  __shared__ __align__(16) u16 Vs[2][64 * 136];   // [d][kperm] (vt pre-swz)

  const int tid = threadIdx.x, lane = tid & 63, w = tid >> 6;
  const int quad = lane >> 4, m16 = lane & 15;

  // Complementary-pair decode (see header comment).
  const int id    = (int)blockIdx.x;  // 0..511
  const int lower = id & 255;
  const int j     = id >> 8;          // co-resident complement bit
  const int X     = lower & 7;        // XCD
  const int vloc  = (lower >> 3) & 3;
  const int kk_   = lower >> 5;       // 0..7
  const int Q     = j ? 15 - kk_ : kk_;   // 128-row q-tile index
  const int v     = X * 4 + vloc;     // (b,h) combo
  const int h     = v & 15;
  const int b     = v >> 4;

  const size_t base  = (size_t)b * 2048 * 1024 + (size_t)h * 64;
  const size_t vbase = (size_t)(h * 64) * 4096 + (size_t)b * 2048;
  const float SC = 0.03125f * LOG2E;
  const f32x4 z4 = {0.f, 0.f, 0.f, 0.f};
  const int srow = tid >> 2, sc = (tid & 3) * 16;

  union { u16x8 u; bf16x8 f; } ones;
#pragma unroll
  for (int k = 0; k < 8; k++) ones.u[k] = 0x3F80;  // bf16 1.0

  const int q0 = Q * 128;
  const int nr = Q + 1;  // rounds of 128 keys

  // Q fragments for both subtiles, straight from global (L2-hit).
  const u16* qsA = &qg[base + (size_t)(q0 + w * 32 + m16) * 1024 + quad * 8];
  const bf16x8 qfA0 = *(const bf16x8*)qsA;
  const bf16x8 qfA1 = *(const bf16x8*)(qsA + 32);
  const u16* qsB = qsA + (size_t)16 * 1024;
  const bf16x8 qfB0 = *(const bf16x8*)qsB;
  const bf16x8 qfB1 = *(const bf16x8*)(qsB + 32);

  // Prefetch round 0 K/V into regs.
  u16x8 kr0, kr1, kr2, kr3, vr0, vr1, vr2, vr3;
  {
    const u16* ks = &kg[base + (size_t)srow * 1024 + sc];
    kr0 = *(const u16x8*)ks; kr1 = *(const u16x8*)(ks + 8);
    const u16* ks2 = ks + (size_t)64 * 1024;
    kr2 = *(const u16x8*)ks2; kr3 = *(const u16x8*)(ks2 + 8);
    const u16* vs = &vt[vbase + (size_t)srow * 4096 + sc];
    vr0 = *(const u16x8*)vs; vr1 = *(const u16x8*)(vs + 8);
    vr2 = *(const u16x8*)(vs + 64); vr3 = *(const u16x8*)(vs + 72);
  }

  f32x4 lA = z4, lB = z4;
  f32x4 OA[4], OB[4];
#pragma unroll
  for (int d = 0; d < 4; d++) { OA[d] = z4; OB[d] = z4; }

  const int qrowA = q0 + w * 32 + quad * 4;  // O store rows (subtile A)
  const int qcolA = q0 + w * 32 + m16;       // softmax q (subtile A)

  int p = 0;
  for (int rr = 0; rr < nr; ++rr) {
    const int k0 = rr * 128;
    // stage round rr into buf p (overlaps other waves' round rr-1 compute)
    u16* ksp = &Ks[p][0];
    u16* vsp = &Vs[p][0];
    *(u16x8*)&ksp[srow * 72 + sc] = kr0;
    *(u16x8*)&ksp[srow * 72 + sc + 8] = kr1;
    *(u16x8*)&ksp[(64 + srow) * 72 + sc] = kr2;
    *(u16x8*)&ksp[(64 + srow) * 72 + sc + 8] = kr3;
    *(u16x8*)&vsp[srow * 136 + sc] = vr0;
    *(u16x8*)&vsp[srow * 136 + sc + 8] = vr1;
    *(u16x8*)&vsp[srow * 136 + 64 + sc] = vr2;
    *(u16x8*)&vsp[srow * 136 + 64 + sc + 8] = vr3;
    if (rr + 1 < nr) {  // prefetch next round; consumed after next barrier
      const u16* ks = &kg[base + (size_t)(k0 + 128 + srow) * 1024 + sc];
      kr0 = *(const u16x8*)ks; kr1 = *(const u16x8*)(ks + 8);
      const u16* ks2 = ks + (size_t)64 * 1024;
      kr2 = *(const u16x8*)ks2; kr3 = *(const u16x8*)(ks2 + 8);
      const u16* vs = &vt[vbase + (size_t)srow * 4096 + k0 + 128 + sc];
      vr0 = *(const u16x8*)vs; vr1 = *(const u16x8*)(vs + 8);
      vr2 = *(const u16x8*)(vs + 64); vr3 = *(const u16x8*)(vs + 72);
    }
    __syncthreads();  // single barrier: buf p staged; prior buf reads done

    // S^T = K Q^T over 128 keys for BOTH subtiles; K frags read ONCE.
    f32x4 SA[8], SB[8];
#pragma unroll
    for (int nt = 0; nt < 8; nt++) {
      const bf16x8 kf0 = *(const bf16x8*)&ksp[(nt * 16 + m16) * 72 + quad * 8];
      const bf16x8 kf1 =
          *(const bf16x8*)&ksp[(nt * 16 + m16) * 72 + 32 + quad * 8];
      SA[nt] = __builtin_amdgcn_mfma_f32_16x16x32_bf16(kf0, qfA0, z4, 0, 0, 0);
      SA[nt] = __builtin_amdgcn_mfma_f32_16x16x32_bf16(kf1, qfA1, SA[nt], 0, 0, 0);
      SB[nt] = __builtin_amdgcn_mfma_f32_16x16x32_bf16(kf0, qfB0, z4, 0, 0, 0);
      SB[nt] = __builtin_amdgcn_mfma_f32_16x16x32_bf16(kf1, qfB1, SB[nt], 0, 0, 0);
    }

    const bool lastr = (rr == nr - 1);

    union { u32v4 u; bf16x8 f; } PA[4], PB[4];
    {  // subtile A: p = exp2(s*SC), mask last round, pack, assemble frags
      uint32_t W[16];
#pragma unroll
      for (int nt = 0; nt < 8; nt++) {
        float pe[4];
#pragma unroll
        for (int r = 0; r < 4; r++) {
          float e = fast_exp2(SA[nt][r] * SC);
          const int key = k0 + nt * 16 + quad * 4 + r;
          if (lastr && key > qcolA) e = 0.f;
          pe[r] = e;
        }
        uint32_t w0, w1;
        asm("v_cvt_pk_bf16_f32 %0, %1, %2" : "=v"(w0) : "v"(pe[0]), "v"(pe[1]));
        asm("v_cvt_pk_bf16_f32 %0, %1, %2" : "=v"(w1) : "v"(pe[2]), "v"(pe[3]));
        W[2 * nt] = w0; W[2 * nt + 1] = w1;
      }
#pragma unroll
      for (int ks = 0; ks < 4; ks++) {
        uint32_t a0 = W[4 * ks], b0 = W[4 * ks + 2];
        uint32_t a1 = W[4 * ks + 1], b1 = W[4 * ks + 3];
        asm("v_permlane32_swap_b32 %0, %1" : "+v"(a0), "+v"(b0));
        asm("v_permlane32_swap_b32 %0, %1" : "+v"(a1), "+v"(b1));
        PA[ks].u = (u32v4){a0, a1, b0, b1};
      }
    }
    {  // subtile B
      const int qcolB = qcolA + 16;
      uint32_t W[16];
#pragma unroll
      for (int nt = 0; nt < 8; nt++) {
        float pe[4];
#pragma unroll
        for (int r = 0; r < 4; r++) {
          float e = fast_exp2(SB[nt][r] * SC);
          const int key = k0 + nt * 16 + quad * 4 + r;
          if (lastr && key > qcolB) e = 0.f;
          pe[r] = e;
        }
        uint32_t w0, w1;
        asm("v_cvt_pk_bf16_f32 %0, %1, %2" : "=v"(w0) : "v"(pe[0]), "v"(pe[1]));
        asm("v_cvt_pk_bf16_f32 %0, %1, %2" : "=v"(w1) : "v"(pe[2]), "v"(pe[3]));
        W[2 * nt] = w0; W[2 * nt + 1] = w1;
      }
#pragma unroll
      for (int ks = 0; ks < 4; ks++) {
        uint32_t a0 = W[4 * ks], b0 = W[4 * ks + 2];
        uint32_t a1 = W[4 * ks + 1], b1 = W[4 * ks + 3];
        asm("v_permlane32_swap_b32 %0, %1" : "+v"(a0), "+v"(b0));
        asm("v_permlane32_swap_b32 %0, %1" : "+v"(a1), "+v"(b1));
        PB[ks].u = (u32v4){a0, a1, b0, b1};
      }
    }

    // l += P * ones (row sums of rounded P)
#pragma unroll
    for (int ks = 0; ks < 4; ks++) {
      lA = __builtin_amdgcn_mfma_f32_16x16x32_bf16(PA[ks].f, ones.f, lA, 0, 0, 0);
      lB = __builtin_amdgcn_mfma_f32_16x16x32_bf16(PB[ks].f, ones.f, lB, 0, 0, 0);
    }

    // O += P V; V frags read ONCE, feed both subtiles.
#pragma unroll
    for (int dt = 0; dt < 4; dt++) {
#pragma unroll
      for (int ks = 0; ks < 4; ks++) {
        const bf16x8 vf =
            *(const bf16x8*)&vsp[(dt * 16 + m16) * 136 + ks * 32 + quad * 8];
        OA[dt] = __builtin_amdgcn_mfma_f32_16x16x32_bf16(PA[ks].f, vf, OA[dt],
                                                         0, 0, 0);
        OB[dt] = __builtin_amdgcn_mfma_f32_16x16x32_bf16(PB[ks].f, vf, OB[dt],
                                                         0, 0, 0);
      }
    }
    p ^= 1;
  }

  float invA[4], invB[4];
#pragma unroll
  for (int r = 0; r < 4; r++) { invA[r] = 1.0f / lA[r]; invB[r] = 1.0f / lB[r]; }

#pragma unroll
  for (int dt = 0; dt < 4; dt++)
#pragma unroll
    for (int r = 0; r < 4; r++) {
      out[base + (size_t)(qrowA + r) * 1024 + dt * 16 + m16] =
          OA[dt][r] * invA[r];
      out[base + (size_t)(qrowA + 16 + r) * 1024 + dt * 16 + m16] =
          OB[dt][r] * invB[r];
    }
}

extern "C" void kernel_launch(void* const* d_in, const int* in_sizes, int n_in,
                              void* d_out, int out_size, void* d_ws, size_t ws_size,
                              hipStream_t stream) {
  const float* x  = (const float*)d_in[0];
  const float* Wq = (const float*)d_in[1];
  const float* Wk = (const float*)d_in[2];
  const float* Wv = (const float*)d_in[3];
  u16* qb  = (u16*)d_ws;                    // [4096][1024] bf16
  u16* kb  = qb  + (size_t)4096 * 1024;     // [4096][1024] bf16
  u16* vtw = kb  + (size_t)4096 * 1024;     // [1024][4096] bf16 (V^T, swap23)
  u16* xc  = vtw + (size_t)4096 * 1024;     // bf16 inputs
  u16* wqc = xc  + (size_t)4096 * 1024;
  u16* wkc = wqc + (size_t)1024 * 1024;
  u16* wvc = wkc + (size_t)1024 * 1024;

  f32_to_bf16<<<dim3(2048, 4), 256, 0, stream>>>(x, Wq, Wk, Wv,
                                                 xc, wqc, wkc, wvc);
  qkv_gemm<<<dim3(768, 1, 1), 256, 0, stream>>>(xc, wqc, wkc, wvc,
                                                qb, kb, vtw);
  rope_inplace<<<dim3(2048, 2), 256, 0, stream>>>(qb, kb);
  flash_attn<<<dim3(512, 1, 1), 256, 0, stream>>>(qb, kb, vtw, (float*)d_out);
}